// Round 8
// baseline (104.693 us; speedup 1.0000x reference)
//
#include <hip/hip_runtime.h>
#include <hip/hip_bf16.h>

// QConv1d: x (8,64,16384) f32, w (64,64,9) f32, bias (64) f32
// out (8,64,16384) f32 = conv1d(x, w, pad=4) * 0.125 + bias
// Round-8: two-pass. Kernel T streams x fp32 [n][c][l] -> x~ bf16 [n][l+16][c]
// (zero-padded halo rows) in d_ws. Kernel G stages x~ rows into LDS with a
// flat b128 copy (no transpose/cvt in the critical kernel, half the bytes,
// L3-warm) then runs the measured-best R5 K-loop. R6 rocprof showed the
// single-pass kernel was a pure latency chain (MfmaUtil 7%, VALU 5%, HBM 17%).
#define C_IN    64
#define L_IN    16384
#define O_OUT   64
#define KTAP    9
#define LTILE   256
#define ROWS    272      // l in [l0-8, l0+264)
#define RSTRIDE 72       // 64 + 8 pad (multiple of 8 -> 16B-aligned b128 rows)
#define XT_ROWS (L_IN + 16)        // per-n rows in x~ (8 zero-pad each side)
#define XT_OFF  131072             // byte offset of x~ within d_ws (w2 below)

typedef short          bf16x8 __attribute__((ext_vector_type(8)));   // MFMA A/B frag
typedef unsigned int   u32x4  __attribute__((ext_vector_type(4)));
typedef float          f32x4  __attribute__((ext_vector_type(4)));   // MFMA C/D frag
typedef float          f32x8v __attribute__((ext_vector_type(8)));

static __device__ __forceinline__ unsigned short f2bf(float f) {
  __hip_bfloat16 h = __float2bfloat16(f);   // round-to-nearest
  return __builtin_bit_cast(unsigned short, h);
}
static __device__ __forceinline__ unsigned int pk2(float lo, float hi) {
  return (unsigned int)f2bf(lo) | ((unsigned int)f2bf(hi) << 16);
}

// ---------------------------------------------------------------------------
// Pre-kernel 1: w[o][c][t] fp32 -> W2[t][o][c] bf16 (c contig), pre-scaled by
// the exact power-of-two 0.125.
// ---------------------------------------------------------------------------
__global__ void w_rearrange(const float* __restrict__ w,
                            unsigned short* __restrict__ w2) {
    int i = blockIdx.x * 256 + threadIdx.x;       // i = t*4096 + o*64 + c
    if (i >= KTAP * O_OUT * C_IN) return;
    int t  = i >> 12;
    int oc = i & 4095;                            // o*64 + c
    w2[i] = f2bf(w[oc * KTAP + t] * 0.125f);
}

// ---------------------------------------------------------------------------
// Pre-kernel 2: x fp32 [n][c][l] -> x~ bf16 [n][row][c], row = l + 8, with
// rows 0..7 and 16392..16399 zeroed (conv halo). One block = 256-l tile.
// No halo, no edge branches: each l written exactly once.
// ---------------------------------------------------------------------------
__global__ __launch_bounds__(256) void x_transpose(
    const float* __restrict__ x, unsigned short* __restrict__ xt) {
  __shared__ __align__(16) unsigned short xs[LTILE][RSTRIDE];
  const int tid = threadIdx.x;
  const int n   = blockIdx.x >> 6;
  const int l0  = (blockIdx.x & 63) << 8;
  const float* xn = x + (size_t)n * C_IN * L_IN;
  unsigned short* xtn = xt + (size_t)n * XT_ROWS * C_IN;

  // stage + transpose one 8x8 unit per thread (256 units: lb 0..31, cb 0..7)
  {
    const int lb = tid >> 3, cb = tid & 7;
    const int c0 = cb << 3, gl0 = l0 + (lb << 3);
    f32x8v v[8];
#pragma unroll
    for (int i = 0; i < 8; ++i)
      v[i] = *reinterpret_cast<const f32x8v*>(xn + (size_t)(c0 + i) * L_IN + gl0);
#pragma unroll
    for (int j = 0; j < 8; ++j) {
      u32x4 wv;
#pragma unroll
      for (int p = 0; p < 4; ++p) wv[p] = pk2(v[2 * p][j], v[2 * p + 1][j]);
      *reinterpret_cast<u32x4*>(&xs[(lb << 3) + j][c0]) = wv;
    }
  }
  __syncthreads();

  // write rows out: 2048 16B-chunks, fully coalesced
#pragma unroll
  for (int it = 0; it < 8; ++it) {
    const int idx = tid + (it << 8);
    const int row = idx >> 3, ci = (idx & 7) << 3;
    u32x4 wv = *reinterpret_cast<const u32x4*>(&xs[row][ci]);
    *reinterpret_cast<u32x4*>(xtn + (size_t)(8 + l0 + row) * C_IN + ci) = wv;
  }
  // zero halo pads (edge tiles only)
  if (l0 == 0 && tid < 64) {
    const int row = tid >> 3, ci = (tid & 7) << 3;
    u32x4 z = (u32x4){0u, 0u, 0u, 0u};
    *reinterpret_cast<u32x4*>(xtn + (size_t)row * C_IN + ci) = z;
  }
  if (l0 == (L_IN - LTILE) && tid < 64) {
    const int row = (L_IN + 8) + (tid >> 3), ci = (tid & 7) << 3;
    u32x4 z = (u32x4){0u, 0u, 0u, 0u};
    *reinterpret_cast<u32x4*>(xtn + (size_t)row * C_IN + ci) = z;
  }
}

// ---------------------------------------------------------------------------
// Main kernel: one block = one n, one 256-wide L tile, all 64 outputs.
// 4 waves in a 2(O) x 2(L) grid; each wave owns 32 O x 128 L. Staging is a
// flat copy of 272 pre-transposed bf16 rows from x~ (L3-warm).
// ---------------------------------------------------------------------------
__global__ __launch_bounds__(256) void qconv_kernel(
    const unsigned short* __restrict__ xt,    // bf16 bits, [n][row][c]
    const unsigned short* __restrict__ w2,    // bf16 bits, pre-scaled
    const float* __restrict__ bias,
    float* __restrict__ out) {

  __shared__ __align__(16) unsigned short xs[ROWS][RSTRIDE];  // bf16 x tile [l][c]

  const int tid = threadIdx.x;
  const int n   = blockIdx.x >> 6;
  const int l0  = (blockIdx.x & 63) << 8;
  // x~ row (l0 - 8) + 8 = l0 maps to xs row 0  =>  xs[r] holds l = l0 - 8 + r
  const unsigned short* src = xt + ((size_t)n * XT_ROWS + l0) * C_IN;

  // ---- Phase 1: flat copy 272 rows x 128 B into LDS (9 b128 per thread) --
#pragma unroll
  for (int it = 0; it < 9; ++it) {
    const int idx = tid + (it << 8);
    if (idx < ROWS * 8) {
      const int row = idx >> 3, ci = (idx & 7) << 3;
      u32x4 v = *reinterpret_cast<const u32x4*>(src + (size_t)row * C_IN + ci);
      *reinterpret_cast<u32x4*>(&xs[row][ci]) = v;
    }
  }
  __syncthreads();

  // ---- Phase 2: MFMA main loop (R5 structure, measured best) -------------
  const int wave = tid >> 6;
  const int lane = tid & 63;
  const int wr   = wave >> 1;       // O half: o in [32*wr, 32*wr+32)
  const int wc   = wave & 1;        // L half: l-offset wc*128
  const int col  = lane & 15;
  const int quad = lane >> 4;

  f32x4 acc[2][8];
#pragma unroll
  for (int m = 0; m < 2; ++m)
#pragma unroll
    for (int lt = 0; lt < 8; ++lt) acc[m][lt] = (f32x4){0.f, 0.f, 0.f, 0.f};

  const int rbase = (wc << 7) + col + 4;

  for (int t = 0; t < KTAP; ++t) {
    bf16x8 a[2][2];
#pragma unroll
    for (int m = 0; m < 2; ++m)
#pragma unroll
      for (int k = 0; k < 2; ++k)
        a[m][k] = *reinterpret_cast<const bf16x8*>(
            w2 + (t << 12) + (((wr << 5) + (m << 4) + col) << 6) + (k << 5) + (quad << 3));

#pragma unroll
    for (int k = 0; k < 2; ++k) {
#pragma unroll
      for (int lt = 0; lt < 8; ++lt) {
        const int r = rbase + t + (lt << 4);
        const bf16x8 b = *reinterpret_cast<const bf16x8*>(&xs[r][(k << 5) + (quad << 3)]);
        acc[0][lt] = __builtin_amdgcn_mfma_f32_16x16x32_bf16(a[0][k], b, acc[0][lt], 0, 0, 0);
        acc[1][lt] = __builtin_amdgcn_mfma_f32_16x16x32_bf16(a[1][k], b, acc[1][lt], 0, 0, 0);
      }
    }
  }

  // ---- Phase 3: epilogue: + bias (0.125 folded into w), fp32 store ------
#pragma unroll
  for (int m = 0; m < 2; ++m) {
    const int obase = (wr << 5) + (m << 4) + (quad << 2);
    float bv[4];
#pragma unroll
    for (int reg = 0; reg < 4; ++reg) bv[reg] = bias[obase + reg];
#pragma unroll
    for (int lt = 0; lt < 8; ++lt) {
      const int l = l0 + (wc << 7) + (lt << 4) + col;
#pragma unroll
      for (int reg = 0; reg < 4; ++reg) {
        const int o = obase + reg;
        out[((size_t)(n * O_OUT + o) << 14) + l] = acc[m][lt][reg] + bv[reg];
      }
    }
  }
}

extern "C" void kernel_launch(void* const* d_in, const int* in_sizes, int n_in,
                              void* d_out, int out_size, void* d_ws, size_t ws_size,
                              hipStream_t stream) {
  const float*    x    = (const float*)d_in[0];
  const float*    w    = (const float*)d_in[1];
  const float*    bias = (const float*)d_in[2];
  float*          out  = (float*)d_out;
  unsigned short* w2   = (unsigned short*)d_ws;                       // 73728 B
  unsigned short* xt   = (unsigned short*)((char*)d_ws + XT_OFF);     // 16.8 MB

  w_rearrange<<<(KTAP * O_OUT * C_IN + 255) / 256, 256, 0, stream>>>(w, w2);
  x_transpose<<<8 * (L_IN / LTILE), 256, 0, stream>>>(x, xt);
  qconv_kernel<<<8 * (L_IN / LTILE), 256, 0, stream>>>(xt, w2, bias, out);
}